// Round 2
// baseline (268.000 us; speedup 1.0000x reference)
//
#include <hip/hip_runtime.h>
#include <math.h>

// ---------------------------------------------------------------------------
// PatchEmbedding: gather 9x9x3 patches from frames, x@W1+b1 -> GELU -> @W2+b2
// B=4, T=16, C=3, H=W=256, N=8192, patch_dim=243, EMBED=768
// Inputs/outputs fp32; t_src int32. Internally bf16 MFMA (no fp32 MFMA on CDNA4).
//
// R1: replaced the 128x128 / 2-barrier GEMM (605 TF, MfmaUtil 22.6%) with the
// 256x256 8-phase counted-vmcnt schedule (T2+T3+T4+T5):
//   - 512 threads = 8 waves (2M x 4N), per-wave 128x64 output, acc[8][4]
//   - LDS 128 KiB: As[2buf][2half][128x64] + Bs same, XOR slot swizzle (T2)
//   - per K-tile: 4 phases {ds_read quadrant frags; stage 1 half-tile (2 gll);
//     s_barrier; lgkmcnt(0)+sched_barrier; setprio(1); 16 MFMA; setprio(0);
//     s_barrier}; quadrant order (0,0),(1,0),(0,1),(1,1) -> reads 12/8/4/0
//   - staging ledger: tile t's halves issued at phases 4t-5..4t-2 (A0,A1,B0,B1);
//     checkpoints vmcnt(4) at phases 4 & 8 guarantee issues <= P-2 => tile
//     landed before its first read at P+1; final iteration ckpt = vmcnt(0).
//   - rule #18: sched_barrier(0) after every inline lgkmcnt/barrier.
// K-order trick unchanged: X and W1T use permuted k' = c*81 + i*9 + j.
// r4 lesson (prev session): no bucket-sorting the gather.
// ---------------------------------------------------------------------------

typedef __attribute__((ext_vector_type(8))) short short8;
typedef __attribute__((ext_vector_type(4))) float floatx4;

#define M_ROWS 32768      // B*N = 4*8192
#define KPAD   256        // patch_dim 243 padded to 256
#define EMB    768

typedef __attribute__((address_space(1))) const void g_void;
typedef __attribute__((address_space(3))) void l_void;

__device__ __forceinline__ unsigned short f2bf(float f) {
    union { float f; unsigned int i; } w;
    w.f = f;
    unsigned int x = w.i;
    x += 0x7fffu + ((x >> 16) & 1u);   // round-to-nearest-even
    return (unsigned short)(x >> 16);
}

// tanh-form GELU: max abs deviation from exact erf-GELU < 1e-3.
__device__ __forceinline__ float gelu_f(float x) {
    float x3 = x * x * x;
    float y  = 1.5957691216f * (x + 0.044715f * x3);   // 2*sqrt(2/pi)*(...)
    float e  = __expf(y);                               // e^{2z}
    float th = 1.0f - 2.0f / (e + 1.0f);                // tanh(z)
    return 0.5f * x * (1.0f + th);
}

// ---- prep: W1 (243x768 f32) -> W1T (768x256 bf16, zero-pad, permuted k') ----
__global__ void k_transpose_w1(const float* __restrict__ W1,
                               unsigned short* __restrict__ W1T) {
    int idx = blockIdx.x * 256 + threadIdx.x;   // 768*256 total
    int n  = idx >> 8;        // 0..767
    int kp = idx & 255;       // permuted k': c*81 + i*9 + j
    unsigned short v = 0;
    if (kp < 243) {
        int c = kp / 81;
        int r = kp - c * 81;
        int i = r / 9;
        int j = r - i * 9;
        int e = i * 27 + j * 3 + c;   // reference order
        v = f2bf(W1[e * EMB + n]);
    }
    W1T[idx] = v;
}

// ---- prep: W2 (768x768 f32) -> W2T (768x768 bf16), LDS-tiled transpose ----
__global__ void k_transpose_w2(const float* __restrict__ W2,
                               unsigned short* __restrict__ W2T) {
    __shared__ float tile[32][33];
    int tx = threadIdx.x & 31, ty = threadIdx.x >> 5;   // 32 x 8
    int k0 = blockIdx.x * 32, n0 = blockIdx.y * 32;
#pragma unroll
    for (int i = 0; i < 4; ++i)
        tile[ty + i * 8][tx] = W2[(size_t)(k0 + ty + i * 8) * EMB + n0 + tx];
    __syncthreads();
#pragma unroll
    for (int i = 0; i < 4; ++i)
        W2T[(size_t)(n0 + ty + i * 8) * EMB + k0 + tx] = f2bf(tile[tx][ty + i * 8]);
}

// ---- gather patches -> X (32768 x 256 bf16), channel-major order k' --------
__global__ void k_gather(const float* __restrict__ frames,
                         const float* __restrict__ coords,
                         const int* __restrict__ t_src,
                         unsigned short* __restrict__ X) {
    int row  = blockIdx.x * 4 + (threadIdx.x >> 6);   // 0..32767
    int lane = threadIdx.x & 63;
    int b = row >> 13;

    float cu = coords[row * 2 + 0];
    float cv = coords[row * 2 + 1];
    int u = (int)(cu * 255.0f);   // exact fp32 math, matches reference
    int v = (int)(cv * 255.0f);
    int t = t_src[row];

    const float* fb = frames + (size_t)(b * 16 + t) * (3 * 256 * 256);
    unsigned short* xr = X + (size_t)row * KPAD;

#pragma unroll
    for (int it = 0; it < 4; ++it) {
        int kp = lane + it * 64;            // permuted index c*81 + i*9 + j
        unsigned short val = 0;
        if (kp < 243) {
            int c = kp / 81;
            int r = kp - c * 81;
            int i = r / 9;
            int j = r - i * 9;
            int y = v + i - 4; y = (y < 0) ? 0 : (y > 255 ? 255 : y);
            int x = u + j - 4; x = (x < 0) ? 0 : (x > 255 ? 255 : x);
            val = f2bf(fb[(size_t)c * 65536 + y * 256 + x]);
        }
        xr[kp] = val;
    }
}

// ---------------------------------------------------------------------------
// 256x256 8-phase GEMM body.
// A: MxK row-major bf16, BT: NxK row-major bf16 (K mult of 128, >= 256).
// ---------------------------------------------------------------------------

#define STAGE_A(B_, H_, KT_) do {                                              \
    __builtin_amdgcn_global_load_lds(                                          \
        (g_void*)(Ag + oS##H_##0 + (size_t)(KT_) * 64),                        \
        (l_void*)(&As[B_][H_][c0 * 512]), 16, 0, 0);                           \
    __builtin_amdgcn_global_load_lds(                                          \
        (g_void*)(Ag + oS##H_##1 + (size_t)(KT_) * 64),                        \
        (l_void*)(&As[B_][H_][c1 * 512]), 16, 0, 0);                           \
} while (0)

#define STAGE_B(B_, H_, KT_) do {                                              \
    __builtin_amdgcn_global_load_lds(                                          \
        (g_void*)(Bg + oS##H_##0 + (size_t)(KT_) * 64),                        \
        (l_void*)(&Bs[B_][H_][c0 * 512]), 16, 0, 0);                           \
    __builtin_amdgcn_global_load_lds(                                          \
        (g_void*)(Bg + oS##H_##1 + (size_t)(KT_) * 64),                        \
        (l_void*)(&Bs[B_][H_][c1 * 512]), 16, 0, 0);                           \
} while (0)

// A fragments for half MH into DST[ks][mi] (8 x ds_read_b128)
#define LDA(DST, B_, MH) do {                                                  \
    _Pragma("unroll")                                                          \
    for (int mi_ = 0; mi_ < 4; ++mi_) {                                        \
        DST[0][mi_] = *(const short8*)&As[B_][wm][(MH)*4096 + mi_*1024 + aof0];\
        DST[1][mi_] = *(const short8*)&As[B_][wm][(MH)*4096 + mi_*1024 + aof1];\
    }                                                                          \
} while (0)

// B fragments for col-half NH into bb[ks][ni] (4 x ds_read_b128)
#define LDB(B_, NH) do {                                                       \
    _Pragma("unroll")                                                          \
    for (int ni_ = 0; ni_ < 2; ++ni_) {                                        \
        bb[0][ni_] = *(const short8*)&Bs[B_][bh][bn64 + (NH)*2048 + ni_*1024 + aof0]; \
        bb[1][ni_] = *(const short8*)&Bs[B_][bh][bn64 + (NH)*2048 + ni_*1024 + aof1]; \
    }                                                                          \
} while (0)

#define MFMA_Q(MH, NH, ASET) do {                                              \
    _Pragma("unroll")                                                          \
    for (int ks_ = 0; ks_ < 2; ++ks_)                                          \
    { _Pragma("unroll")                                                        \
      for (int mi_ = 0; mi_ < 4; ++mi_)                                        \
      { _Pragma("unroll")                                                      \
        for (int ni_ = 0; ni_ < 2; ++ni_)                                      \
            acc[(MH)*4 + mi_][(NH)*2 + ni_] =                                  \
                __builtin_amdgcn_mfma_f32_16x16x32_bf16(                       \
                    ASET[ks_][mi_], bb[ks_][ni_],                              \
                    acc[(MH)*4 + mi_][(NH)*2 + ni_], 0, 0, 0);                 \
      } }                                                                      \
} while (0)

#define SYNC_MFMA(MH, NH, ASET) do {                                           \
    __builtin_amdgcn_s_barrier();                                              \
    asm volatile("s_waitcnt lgkmcnt(0)" ::: "memory");                         \
    __builtin_amdgcn_sched_barrier(0);                                         \
    __builtin_amdgcn_s_setprio(1);                                             \
    MFMA_Q(MH, NH, ASET);                                                      \
    __builtin_amdgcn_s_setprio(0);                                             \
} while (0)

#define END_PHASE do {                                                         \
    __builtin_amdgcn_s_barrier();                                              \
    __builtin_amdgcn_sched_barrier(0);                                         \
} while (0)

#define CKPT(N_) do {                                                          \
    asm volatile("s_waitcnt vmcnt(" #N_ ")" ::: "memory");                     \
    __builtin_amdgcn_s_barrier();                                              \
    __builtin_amdgcn_sched_barrier(0);                                         \
} while (0)

// steady iteration: tiles t0 (buf0), t0+1 (buf1); stages t0+1 B, t0+2, t0+3 A
#define ITER_STEADY(T0) do {                                                   \
    /* p1 */ LDA(a0, 0, 0); LDB(0, 0); STAGE_B(1, 0, (T0)+1);                  \
             SYNC_MFMA(0, 0, a0); END_PHASE;                                   \
    /* p2 */ LDA(a1, 0, 1); STAGE_B(1, 1, (T0)+1);                             \
             SYNC_MFMA(1, 0, a1); END_PHASE;                                   \
    /* p3 */ LDB(0, 1); STAGE_A(0, 0, (T0)+2);                                 \
             SYNC_MFMA(0, 1, a0); END_PHASE;                                   \
    /* p4 */ STAGE_A(0, 1, (T0)+2);                                            \
             SYNC_MFMA(1, 1, a1); CKPT(4);                                     \
    /* p5 */ LDA(a0, 1, 0); LDB(1, 0); STAGE_B(0, 0, (T0)+2);                  \
             SYNC_MFMA(0, 0, a0); END_PHASE;                                   \
    /* p6 */ LDA(a1, 1, 1); STAGE_B(0, 1, (T0)+2);                             \
             SYNC_MFMA(1, 0, a1); END_PHASE;                                   \
    /* p7 */ LDB(1, 1); STAGE_A(1, 0, (T0)+3);                                 \
             SYNC_MFMA(0, 1, a0); END_PHASE;                                   \
    /* p8 */ STAGE_A(1, 1, (T0)+3);                                            \
             SYNC_MFMA(1, 1, a1); CKPT(4);                                     \
} while (0)

// final iteration: tiles KT-2 (buf0), KT-1 (buf1); only t0+1 B stages remain
#define ITER_FINAL(T0) do {                                                    \
    /* p1 */ LDA(a0, 0, 0); LDB(0, 0); STAGE_B(1, 0, (T0)+1);                  \
             SYNC_MFMA(0, 0, a0); END_PHASE;                                   \
    /* p2 */ LDA(a1, 0, 1); STAGE_B(1, 1, (T0)+1);                             \
             SYNC_MFMA(1, 0, a1); END_PHASE;                                   \
    /* p3 */ LDB(0, 1);                                                        \
             SYNC_MFMA(0, 1, a0); END_PHASE;                                   \
    /* p4 */ SYNC_MFMA(1, 1, a1); CKPT(0);                                     \
    /* p5 */ LDA(a0, 1, 0); LDB(1, 0);                                         \
             SYNC_MFMA(0, 0, a0); END_PHASE;                                   \
    /* p6 */ LDA(a1, 1, 1);                                                    \
             SYNC_MFMA(1, 0, a1); END_PHASE;                                   \
    /* p7 */ LDB(1, 1);                                                        \
             SYNC_MFMA(0, 1, a0); END_PHASE;                                   \
    /* p8 */ SYNC_MFMA(1, 1, a1);                                              \
} while (0)

template <int K, bool GELU_, bool OUT_F32>
static __device__ __forceinline__
void gemm8_body(const unsigned short* __restrict__ A,
                const unsigned short* __restrict__ BT,
                const float* __restrict__ bias,
                void* __restrict__ Cv) {
    constexpr int KT  = K / 64;
    constexpr int NIT = KT / 2;
    static_assert(KT >= 4 && (KT & 1) == 0, "K must be multiple of 128, >=256");

    __shared__ unsigned short As[2][2][128 * 64];   // 64 KiB
    __shared__ unsigned short Bs[2][2][128 * 64];   // 64 KiB

    const int tid  = threadIdx.x;
    const int wave = tid >> 6;
    const int lane = tid & 63;
    const int wm = wave >> 2;           // 0..1  (M half, 128 rows)
    const int wn = wave & 3;            // 0..3  (N quarter, 64 cols)
    const int bh = wn >> 1;             // B half-region index
    const int bn64 = (wn & 1) * 4096;   // offset inside B half (64 rows * 64)
    const int lm = lane & 15;
    const int lq = lane >> 4;

    const int m0 = blockIdx.x * 256;
    const int n0 = blockIdx.y * 256;

    // LDS fragment byte offsets (in shorts): row lm, slot (ks*4+lq)^(lm&7)
    const int aof0 = lm * 64 + (((0 << 2) + lq) ^ (lm & 7)) * 8;
    const int aof1 = lm * 64 + (((1 << 2) + lq) ^ (lm & 7)) * 8;

    // staging geometry: chunk c = wave*2+i covers rows c*8..c*8+7 of a half
    const int rl = lane >> 3;           // row within chunk
    const int pl = lane & 7;            // physical 16B slot
    const int c0 = wave * 2, c1 = wave * 2 + 1;
    const int r0 = c0 * 8 + rl, r1 = c1 * 8 + rl;
    const size_t slog8 = (size_t)((pl ^ rl) * 8);   // logical slot * 8 elems
    const size_t oS00 = (size_t)(r0)       * K + slog8;   // h=0, i=0
    const size_t oS01 = (size_t)(r1)       * K + slog8;   // h=0, i=1
    const size_t oS10 = (size_t)(128 + r0) * K + slog8;   // h=1, i=0
    const size_t oS11 = (size_t)(128 + r1) * K + slog8;   // h=1, i=1

    const unsigned short* Ag = A  + (size_t)m0 * K;
    const unsigned short* Bg = BT + (size_t)n0 * K;

    floatx4 acc[8][4];
#pragma unroll
    for (int i = 0; i < 8; ++i)
#pragma unroll
        for (int j = 0; j < 4; ++j)
            acc[i][j] = (floatx4){0.f, 0.f, 0.f, 0.f};

    short8 a0[2][4], a1[2][4], bb[2][2];

    // ---- prologue: tile0 (4 halves) + tile1 A halves => 12 gll in flight
    STAGE_A(0, 0, 0); STAGE_A(0, 1, 0);
    STAGE_B(0, 0, 0); STAGE_B(0, 1, 0);
    STAGE_A(1, 0, 1); STAGE_A(1, 1, 1);
    asm volatile("s_waitcnt vmcnt(4)" ::: "memory");   // tile0 landed
    __builtin_amdgcn_s_barrier();
    __builtin_amdgcn_sched_barrier(0);

#pragma unroll 1
    for (int it = 0; it < NIT - 1; ++it) {
        const int t0 = 2 * it;
        ITER_STEADY(t0);
    }
    ITER_FINAL(2 * (NIT - 1));

    // ---- epilogue: D row = m0+wm*128+mg*16+lq*4+r, col = n0+wn*64+ng*16+lm
#pragma unroll
    for (int ng = 0; ng < 4; ++ng) {
        const int col = n0 + wn * 64 + ng * 16 + lm;
        const float bs = bias[col];
#pragma unroll
        for (int mg = 0; mg < 8; ++mg) {
            const int rowb = m0 + wm * 128 + mg * 16 + lq * 4;
#pragma unroll
            for (int r2 = 0; r2 < 4; ++r2) {
                float x = acc[mg][ng][r2] + bs;
                if (GELU_)
                    x = gelu_f(x);
                size_t idx = (size_t)(rowb + r2) * EMB + col;
                if (OUT_F32)
                    ((float*)Cv)[idx] = x;
                else
                    ((unsigned short*)Cv)[idx] = f2bf(x);
            }
        }
    }
}

// distinct names so rocprof shows each GEMM separately
__global__ __launch_bounds__(512, 2)
void k_gemm1(const unsigned short* __restrict__ A, const unsigned short* __restrict__ BT,
             const float* __restrict__ bias, unsigned short* __restrict__ C) {
    gemm8_body<KPAD, true, false>(A, BT, bias, (void*)C);
}

__global__ __launch_bounds__(512, 2)
void k_gemm2(const unsigned short* __restrict__ A, const unsigned short* __restrict__ BT,
             const float* __restrict__ bias, float* __restrict__ C) {
    gemm8_body<EMB, false, true>(A, BT, bias, (void*)C);
}

// ---------------------------------------------------------------------------
extern "C" void kernel_launch(void* const* d_in, const int* in_sizes, int n_in,
                              void* d_out, int out_size, void* d_ws, size_t ws_size,
                              hipStream_t stream) {
    const float* frames = (const float*)d_in[0];
    const float* coords = (const float*)d_in[1];
    const int*   t_src  = (const int*)d_in[2];
    const float* W1     = (const float*)d_in[3];
    const float* b1     = (const float*)d_in[4];
    const float* W2     = (const float*)d_in[5];
    const float* b2     = (const float*)d_in[6];
    float* out = (float*)d_out;

    char* ws = (char*)d_ws;
    // workspace layout:
    //   X    : 32768*256*2 = 16,777,216 B  (bf16, permuted k')
    //   Hbuf : 32768*768*2 = 50,331,648 B  (bf16)
    //   W1T  : 768*256*2   =    393,216 B  (bf16, permuted k')
    //   W2T  : 768*768*2   =  1,179,648 B  (bf16)
    unsigned short* X    = (unsigned short*)(ws);
    unsigned short* Hbuf = (unsigned short*)(ws + 16777216);
    unsigned short* W1T  = (unsigned short*)(ws + 16777216 + 50331648);
    unsigned short* W2T  = (unsigned short*)(ws + 16777216 + 50331648 + 393216);

    // prep transposes (tiny)
    k_transpose_w1<<<768, 256, 0, stream>>>(W1, W1T);
    k_transpose_w2<<<dim3(24, 24), 256, 0, stream>>>(W2, W2T);

    // gather patches (one wave per row, channel-major element order)
    k_gather<<<M_ROWS / 4, 256, 0, stream>>>(frames, coords, t_src, X);

    // GEMM1: H = gelu(X @ W1 + b1)   (K = 256 padded), bf16 out
    k_gemm1<<<dim3(M_ROWS / 256, EMB / 256), 512, 0, stream>>>(X, W1T, b1, Hbuf);

    // GEMM2: out = H @ W2 + b2       (K = 768), fp32 out
    k_gemm2<<<dim3(M_ROWS / 256, EMB / 256), 512, 0, stream>>>(Hbuf, W2T, b2, out);
}

// Round 3
// 228.728 us; speedup vs baseline: 1.1717x; 1.1717x over previous
//
#include <hip/hip_runtime.h>
#include <math.h>

// ---------------------------------------------------------------------------
// PatchEmbedding: gather 9x9x3 patches from frames, x@W1+b1 -> GELU -> @W2+b2
// B=4, T=16, C=3, H=W=256, N=8192, patch_dim=243, EMBED=768
// Inputs/outputs fp32; t_src int32. Internally bf16 MFMA (no fp32 MFMA on CDNA4).
//
// R2 post-mortem: 8-phase 256^2 port REGRESSED (gemm2 64->74us, MfmaUtil 19%).
// Regime mismatch: grid 384 @ 1 block/CU (1.5 rounds, no inter-block overlap),
// K=768 -> only 6 iterations (pipeline never amortizes), big fp32 epilogue
// burst exposed. Both R1/R2 run at traffic/achieved-BW with BW only
// ~2.3-2.9 TB/s and MfmaUtil+VALUBusy low => LATENCY-bound, not schedule-bound.
//
// R3: revert to the proven R1 dataflow (128^2 tile, syncthreads dbuf,
// gll-after-barrier, XOR slot swizzle) with two concurrency levers:
//   - 8 waves / block (512 thr), per-wave 64x32, acc[4][2]: LDS still 64KB ->
//     2 blocks/CU but 16 waves/CU (4/SIMD) = 2x TLP for latency hiding.
//   - XCD-chunked swizzle, y-fastest: the 6 blocks sharing an A-panel are
//     consecutive logical tiles on one XCD -> A re-reads become L2 hits.
// K-order trick unchanged: X and W1T use permuted k' = c*81 + i*9 + j.
// r4 lesson (prev session): no bucket-sorting the gather.
// ---------------------------------------------------------------------------

typedef __attribute__((ext_vector_type(8))) short short8;
typedef __attribute__((ext_vector_type(4))) float floatx4;

#define M_ROWS 32768      // B*N = 4*8192
#define KPAD   256        // patch_dim 243 padded to 256
#define EMB    768

typedef __attribute__((address_space(1))) const void g_void;
typedef __attribute__((address_space(3))) void l_void;

__device__ __forceinline__ unsigned short f2bf(float f) {
    union { float f; unsigned int i; } w;
    w.f = f;
    unsigned int x = w.i;
    x += 0x7fffu + ((x >> 16) & 1u);   // round-to-nearest-even
    return (unsigned short)(x >> 16);
}

// tanh-form GELU: max abs deviation from exact erf-GELU < 1e-3.
__device__ __forceinline__ float gelu_f(float x) {
    float x3 = x * x * x;
    float y  = 1.5957691216f * (x + 0.044715f * x3);   // 2*sqrt(2/pi)*(...)
    float e  = __expf(y);                               // e^{2z}
    float th = 1.0f - 2.0f / (e + 1.0f);                // tanh(z)
    return 0.5f * x * (1.0f + th);
}

// ---- prep: W1 (243x768 f32) -> W1T (768x256 bf16, zero-pad, permuted k') ----
__global__ void k_transpose_w1(const float* __restrict__ W1,
                               unsigned short* __restrict__ W1T) {
    int idx = blockIdx.x * 256 + threadIdx.x;   // 768*256 total
    int n  = idx >> 8;        // 0..767
    int kp = idx & 255;       // permuted k': c*81 + i*9 + j
    unsigned short v = 0;
    if (kp < 243) {
        int c = kp / 81;
        int r = kp - c * 81;
        int i = r / 9;
        int j = r - i * 9;
        int e = i * 27 + j * 3 + c;   // reference order
        v = f2bf(W1[e * EMB + n]);
    }
    W1T[idx] = v;
}

// ---- prep: W2 (768x768 f32) -> W2T (768x768 bf16), LDS-tiled transpose ----
__global__ void k_transpose_w2(const float* __restrict__ W2,
                               unsigned short* __restrict__ W2T) {
    __shared__ float tile[32][33];
    int tx = threadIdx.x & 31, ty = threadIdx.x >> 5;   // 32 x 8
    int k0 = blockIdx.x * 32, n0 = blockIdx.y * 32;
#pragma unroll
    for (int i = 0; i < 4; ++i)
        tile[ty + i * 8][tx] = W2[(size_t)(k0 + ty + i * 8) * EMB + n0 + tx];
    __syncthreads();
#pragma unroll
    for (int i = 0; i < 4; ++i)
        W2T[(size_t)(n0 + ty + i * 8) * EMB + k0 + tx] = f2bf(tile[tx][ty + i * 8]);
}

// ---- gather patches -> X (32768 x 256 bf16), channel-major order k' --------
__global__ void k_gather(const float* __restrict__ frames,
                         const float* __restrict__ coords,
                         const int* __restrict__ t_src,
                         unsigned short* __restrict__ X) {
    int row  = blockIdx.x * 4 + (threadIdx.x >> 6);   // 0..32767
    int lane = threadIdx.x & 63;
    int b = row >> 13;

    float cu = coords[row * 2 + 0];
    float cv = coords[row * 2 + 1];
    int u = (int)(cu * 255.0f);   // exact fp32 math, matches reference
    int v = (int)(cv * 255.0f);
    int t = t_src[row];

    const float* fb = frames + (size_t)(b * 16 + t) * (3 * 256 * 256);
    unsigned short* xr = X + (size_t)row * KPAD;

#pragma unroll
    for (int it = 0; it < 4; ++it) {
        int kp = lane + it * 64;            // permuted index c*81 + i*9 + j
        unsigned short val = 0;
        if (kp < 243) {
            int c = kp / 81;
            int r = kp - c * 81;
            int i = r / 9;
            int j = r - i * 9;
            int y = v + i - 4; y = (y < 0) ? 0 : (y > 255 ? 255 : y);
            int x = u + j - 4; x = (x < 0) ? 0 : (x > 255 ? 255 : x);
            val = f2bf(fb[(size_t)c * 65536 + y * 256 + x]);
        }
        xr[kp] = val;
    }
}

// ---- MFMA GEMM body (shared by k_gemm1 / k_gemm2) -------------------------
// 128x128 tile / 8 waves (each 64x32 via 4x2 16x16x32). Double-buffered LDS,
// global_load_lds width=16 issued right after the single per-iteration
// barrier. XOR swizzle: logical 16B slot s of row r at physical slot s^(r&7).
// Grid is FLAT 1536 = 256 M-tiles x 6 N-tiles, XCD-chunk swizzled, y-fastest.
template <int K, bool GELU_, bool OUT_F32>
static __device__ __forceinline__
void gemm_body(const unsigned short* __restrict__ A,
               const unsigned short* __restrict__ BT,
               const float* __restrict__ bias,
               void* __restrict__ Cv) {
    __shared__ unsigned short As[2][128 * 64];   // 16 KB each
    __shared__ unsigned short Bs[2][128 * 64];   // total LDS = 64 KB

    const int tid  = threadIdx.x;
    const int wave = tid >> 6;      // 0..7
    const int lane = tid & 63;
    const int wr = wave >> 2;       // 0..1 : M half (64 rows)
    const int wc = wave & 3;        // 0..3 : N quarter (32 cols)
    const int lm = lane & 15;
    const int lq = lane >> 4;

    // XCD-chunked bijective swizzle (nwg=1536, 192/XCD), y-fastest so the 6
    // blocks sharing one A-panel are consecutive logical tiles -> same XCD L2.
    const int bid = blockIdx.x;
    const int swz = (bid & 7) * 192 + (bid >> 3);
    const int by  = swz % 6;
    const int bx  = swz / 6;
    const int m0 = bx * 128;
    const int n0 = by * 128;

    floatx4 acc[4][2];
#pragma unroll
    for (int i = 0; i < 4; ++i)
#pragma unroll
        for (int j = 0; j < 2; ++j)
            acc[i][j] = (floatx4){0.f, 0.f, 0.f, 0.f};

    const unsigned short* Ag = A  + (size_t)m0 * K;
    const unsigned short* Bg = BT + (size_t)n0 * K;

    // staging: chunk c = i*8 + wave covers rows c*8..c*8+7 (8 rows x 64 cols).
    // lane l -> row c*8 + (l>>3), physical 16B slot l&7; source pre-swizzled.
    const int rl    = lane >> 3;
    const int pl    = lane & 7;
    const int lslot = pl ^ rl;           // (r&7) == rl for all chunks
    const int c0 = wave;                 // i = 0
    const int c1 = 8 + wave;             // i = 1
    const size_t o0 = (size_t)(c0 * 8 + rl) * K + (lslot << 3);
    const size_t o1 = (size_t)(c1 * 8 + rl) * K + (lslot << 3);

    // prologue: issue tile 0 into buffer 0
    __builtin_amdgcn_global_load_lds((g_void*)(Ag + o0), (l_void*)(&As[0][c0 * 512]), 16, 0, 0);
    __builtin_amdgcn_global_load_lds((g_void*)(Ag + o1), (l_void*)(&As[0][c1 * 512]), 16, 0, 0);
    __builtin_amdgcn_global_load_lds((g_void*)(Bg + o0), (l_void*)(&Bs[0][c0 * 512]), 16, 0, 0);
    __builtin_amdgcn_global_load_lds((g_void*)(Bg + o1), (l_void*)(&Bs[0][c1 * 512]), 16, 0, 0);

    int buf = 0;
    for (int k0 = 0; k0 < K; k0 += 64) {
        __syncthreads();   // drains gll for tile(k0), closes reads of buf^1

        if (k0 + 64 < K) {
            __builtin_amdgcn_global_load_lds((g_void*)(Ag + o0 + k0 + 64),
                                             (l_void*)(&As[buf ^ 1][c0 * 512]), 16, 0, 0);
            __builtin_amdgcn_global_load_lds((g_void*)(Ag + o1 + k0 + 64),
                                             (l_void*)(&As[buf ^ 1][c1 * 512]), 16, 0, 0);
            __builtin_amdgcn_global_load_lds((g_void*)(Bg + o0 + k0 + 64),
                                             (l_void*)(&Bs[buf ^ 1][c0 * 512]), 16, 0, 0);
            __builtin_amdgcn_global_load_lds((g_void*)(Bg + o1 + k0 + 64),
                                             (l_void*)(&Bs[buf ^ 1][c1 * 512]), 16, 0, 0);
        }

#pragma unroll
        for (int ks = 0; ks < 2; ++ks) {         // two K=32 steps per BK=64
            short8 af[4], bfr[2];
#pragma unroll
            for (int mi = 0; mi < 4; ++mi) {
                int row = wr * 64 + mi * 16 + lm;
                int ps  = ((ks << 2) + lq) ^ (row & 7);
                af[mi] = *(const short8*)(&As[buf][row * 64 + (ps << 3)]);
            }
#pragma unroll
            for (int ni = 0; ni < 2; ++ni) {
                int row = wc * 32 + ni * 16 + lm;
                int ps  = ((ks << 2) + lq) ^ (row & 7);
                bfr[ni] = *(const short8*)(&Bs[buf][row * 64 + (ps << 3)]);
            }
#pragma unroll
            for (int mi = 0; mi < 4; ++mi)
#pragma unroll
                for (int ni = 0; ni < 2; ++ni)
                    acc[mi][ni] = __builtin_amdgcn_mfma_f32_16x16x32_bf16(
                        af[mi], bfr[ni], acc[mi][ni], 0, 0, 0);
        }
        buf ^= 1;
    }

    // epilogue: D[row][col], row = lq*4 + r, col = lm within each 16x16 tile
#pragma unroll
    for (int ni = 0; ni < 2; ++ni) {
        int col = n0 + wc * 32 + ni * 16 + lm;
        float bs = bias[col];
#pragma unroll
        for (int mi = 0; mi < 4; ++mi) {
            int rowb = m0 + wr * 64 + mi * 16 + lq * 4;
#pragma unroll
            for (int r = 0; r < 4; ++r) {
                float x = acc[mi][ni][r] + bs;
                if (GELU_)
                    x = gelu_f(x);
                size_t idx = (size_t)(rowb + r) * EMB + col;
                if (OUT_F32)
                    ((float*)Cv)[idx] = x;
                else
                    ((unsigned short*)Cv)[idx] = f2bf(x);
            }
        }
    }
}

// distinct names so rocprof shows each GEMM separately
__global__ __launch_bounds__(512, 4)
void k_gemm1(const unsigned short* __restrict__ A, const unsigned short* __restrict__ BT,
             const float* __restrict__ bias, unsigned short* __restrict__ C) {
    gemm_body<KPAD, true, false>(A, BT, bias, (void*)C);
}

__global__ __launch_bounds__(512, 4)
void k_gemm2(const unsigned short* __restrict__ A, const unsigned short* __restrict__ BT,
             const float* __restrict__ bias, float* __restrict__ C) {
    gemm_body<EMB, false, true>(A, BT, bias, (void*)C);
}

// ---------------------------------------------------------------------------
extern "C" void kernel_launch(void* const* d_in, const int* in_sizes, int n_in,
                              void* d_out, int out_size, void* d_ws, size_t ws_size,
                              hipStream_t stream) {
    const float* frames = (const float*)d_in[0];
    const float* coords = (const float*)d_in[1];
    const int*   t_src  = (const int*)d_in[2];
    const float* W1     = (const float*)d_in[3];
    const float* b1     = (const float*)d_in[4];
    const float* W2     = (const float*)d_in[5];
    const float* b2     = (const float*)d_in[6];
    float* out = (float*)d_out;

    char* ws = (char*)d_ws;
    // workspace layout:
    //   X    : 32768*256*2 = 16,777,216 B  (bf16, permuted k')
    //   Hbuf : 32768*768*2 = 50,331,648 B  (bf16)
    //   W1T  : 768*256*2   =    393,216 B  (bf16, permuted k')
    //   W2T  : 768*768*2   =  1,179,648 B  (bf16)
    unsigned short* X    = (unsigned short*)(ws);
    unsigned short* Hbuf = (unsigned short*)(ws + 16777216);
    unsigned short* W1T  = (unsigned short*)(ws + 16777216 + 50331648);
    unsigned short* W2T  = (unsigned short*)(ws + 16777216 + 50331648 + 393216);

    // prep transposes (tiny)
    k_transpose_w1<<<768, 256, 0, stream>>>(W1, W1T);
    k_transpose_w2<<<dim3(24, 24), 256, 0, stream>>>(W2, W2T);

    // gather patches (one wave per row, channel-major element order)
    k_gather<<<M_ROWS / 4, 256, 0, stream>>>(frames, coords, t_src, X);

    // GEMM1: H = gelu(X @ W1 + b1)   (K = 256 padded), bf16 out
    k_gemm1<<<1536, 512, 0, stream>>>(X, W1T, b1, Hbuf);

    // GEMM2: out = H @ W2 + b2       (K = 768), fp32 out
    k_gemm2<<<1536, 512, 0, stream>>>(Hbuf, W2T, b2, out);
}